// Round 1
// baseline (4697.666 us; speedup 1.0000x reference)
//
#include <hip/hip_runtime.h>
#include <math.h>

#define C_DIM 256
#define STEPS 20
#define RPW 16            // rows per wave
#define WAVES_PER_WG 4
#define ROWS_PER_WG (RPW * WAVES_PER_WG)   // 64

__global__ __launch_bounds__(256, 2) void cml_kernel(
    const float* __restrict__ drive,
    const float* __restrict__ r_,
    const float* __restrict__ eps_,
    const float* __restrict__ beta_,
    const float* __restrict__ Kl,
    const float* __restrict__ W,
    float* __restrict__ out)
{
    // wave-private row blocks: no __syncthreads anywhere
    __shared__ float A[WAVES_PER_WG][RPW][C_DIM];   // 64 KiB

    const int tid  = (int)threadIdx.x;
    const int wv   = tid >> 6;
    const int lane = tid & 63;
    const int c0   = lane << 2;                      // 4 contiguous channels per lane
    const size_t rowBase = (size_t)blockIdx.x * ROWS_PER_WG + (size_t)wv * RPW;

    float (*Aw)[C_DIM] = A[wv];

    // per-channel params for this lane's 4 channels
    const float4 r4 = *reinterpret_cast<const float4*>(r_   + c0);
    const float4 e4 = *reinterpret_cast<const float4*>(eps_ + c0);
    const float4 b4 = *reinterpret_cast<const float4*>(beta_+ c0);
    const float k0 = Kl[0], k1 = Kl[1], k2 = Kl[2], k3 = Kl[3], k4 = Kl[4];

    const float rr[4] = {r4.x, r4.y, r4.z, r4.w};
    const float oe[4] = {1.f - e4.x, 1.f - e4.y, 1.f - e4.z, 1.f - e4.w};
    const float eh[4] = {0.5f*e4.x, 0.5f*e4.y, 0.5f*e4.z, 0.5f*e4.w};  // eps*0.5 folded
    const float bt[4] = {b4.x, b4.y, b4.z, b4.w};
    const float ob[4] = {1.f - b4.x, 1.f - b4.y, 1.f - b4.z, 1.f - b4.w};

    // init: grid = drive
    #pragma unroll
    for (int i = 0; i < RPW; ++i) {
        const float4 d4 = *reinterpret_cast<const float4*>(drive + (rowBase + i) * C_DIM + c0);
        *reinterpret_cast<float4*>(&Aw[i][c0]) = d4;
    }
    asm volatile("" ::: "memory");

    #pragma unroll 1
    for (int s = 0; s < STEPS; ++s) {
        // ---- phase 1: logistic map, in place (own channels only) ----
        #pragma unroll
        for (int i = 0; i < RPW; ++i) {
            float4 g4 = *reinterpret_cast<float4*>(&Aw[i][c0]);
            float4 m4;
            m4.x = rr[0] * g4.x * (1.f - g4.x);
            m4.y = rr[1] * g4.y * (1.f - g4.y);
            m4.z = rr[2] * g4.z * (1.f - g4.z);
            m4.w = rr[3] * g4.w * (1.f - g4.w);
            *reinterpret_cast<float4*>(&Aw[i][c0]) = m4;
        }
        asm volatile("" ::: "memory");

        // ---- prefetch drive rows (consumed in phase 3; latency hides under matvec) ----
        float dr[RPW][4];
        #pragma unroll
        for (int i = 0; i < RPW; ++i) {
            const float4 d4 = *reinterpret_cast<const float4*>(drive + (rowBase + i) * C_DIM + c0);
            dr[i][0] = d4.x; dr[i][1] = d4.y; dr[i][2] = d4.z; dr[i][3] = d4.w;
        }

        // ---- phase 2: global coupling matvec  acc = mapped @ W ----
        float acc[RPW][4];
        #pragma unroll
        for (int i = 0; i < RPW; ++i) {
            acc[i][0] = 0.f; acc[i][1] = 0.f; acc[i][2] = 0.f; acc[i][3] = 0.f;
        }

        #pragma unroll 2
        for (int kb = 0; kb < C_DIM / 4; ++kb) {
            const int k = kb << 2;
            float wrow[4][4];
            #pragma unroll
            for (int dk = 0; dk < 4; ++dk) {
                const float4 w4 = *reinterpret_cast<const float4*>(W + (size_t)(k + dk) * C_DIM + c0);
                wrow[dk][0] = w4.x; wrow[dk][1] = w4.y; wrow[dk][2] = w4.z; wrow[dk][3] = w4.w;
            }
            #pragma unroll
            for (int i = 0; i < RPW; ++i) {
                const float4 m4 = *reinterpret_cast<float4*>(&Aw[i][k]);  // LDS broadcast
                const float mm[4] = {m4.x, m4.y, m4.z, m4.w};
                #pragma unroll
                for (int dk = 0; dk < 4; ++dk) {
                    acc[i][0] = fmaf(mm[dk], wrow[dk][0], acc[i][0]);
                    acc[i][1] = fmaf(mm[dk], wrow[dk][1], acc[i][1]);
                    acc[i][2] = fmaf(mm[dk], wrow[dk][2], acc[i][2]);
                    acc[i][3] = fmaf(mm[dk], wrow[dk][3], acc[i][3]);
                }
            }
        }

        // ---- phase 3: circular conv + physics update ----
        #pragma unroll
        for (int i = 0; i < RPW; ++i) {
            float v[8];
            #pragma unroll
            for (int d = 0; d < 8; ++d) {
                v[d] = Aw[i][(c0 + d - 2) & (C_DIM - 1)];
            }
            float ng[4];
            #pragma unroll
            for (int t = 0; t < 4; ++t) {
                const float loc = fmaf(k0, v[t],
                                  fmaf(k1, v[t+1],
                                  fmaf(k2, v[t+2],
                                  fmaf(k3, v[t+3], k4 * v[t+4]))));
                const float m    = v[t+2];
                const float ch   = loc + acc[i][t];                  // local + gcc
                const float phys = fmaf(oe[t], m, eh[t] * ch);       // (1-eps)m + eps*0.5*(...)
                ng[t] = fmaf(ob[t], phys, bt[t] * dr[i][t]);
            }
            asm volatile("" ::: "memory");   // all reads of row i precede its overwrite
            float4 s4; s4.x = ng[0]; s4.y = ng[1]; s4.z = ng[2]; s4.w = ng[3];
            *reinterpret_cast<float4*>(&Aw[i][c0]) = s4;
        }
        asm volatile("" ::: "memory");
    }

    // ---- epilogue: clip + store ----
    #pragma unroll
    for (int i = 0; i < RPW; ++i) {
        float4 g4 = *reinterpret_cast<float4*>(&Aw[i][c0]);
        g4.x = fminf(fmaxf(g4.x, 1e-4f), 1.f - 1e-4f);
        g4.y = fminf(fmaxf(g4.y, 1e-4f), 1.f - 1e-4f);
        g4.z = fminf(fmaxf(g4.z, 1e-4f), 1.f - 1e-4f);
        g4.w = fminf(fmaxf(g4.w, 1e-4f), 1.f - 1e-4f);
        *reinterpret_cast<float4*>(out + (rowBase + i) * C_DIM + c0) = g4;
    }
}

extern "C" void kernel_launch(void* const* d_in, const int* in_sizes, int n_in,
                              void* d_out, int out_size, void* d_ws, size_t ws_size,
                              hipStream_t stream) {
    (void)n_in; (void)d_ws; (void)ws_size; (void)out_size;
    const float* drive = (const float*)d_in[0];
    const float* r     = (const float*)d_in[1];
    const float* eps   = (const float*)d_in[2];
    const float* beta  = (const float*)d_in[3];
    const float* Kl    = (const float*)d_in[4];
    const float* W     = (const float*)d_in[5];
    float* out = (float*)d_out;

    const int nrows = in_sizes[0] / C_DIM;          // 131072
    dim3 grid((unsigned)(nrows / ROWS_PER_WG));     // 2048 WGs
    cml_kernel<<<grid, dim3(256), 0, stream>>>(drive, r, eps, beta, Kl, W, out);
}

// Round 2
// 3461.183 us; speedup vs baseline: 1.3572x; 1.3572x over previous
//
#include <hip/hip_runtime.h>

#define C_DIM 256
#define STEPS 20

typedef _Float16 f16;
typedef f16 f16x8 __attribute__((ext_vector_type(8)));
typedef float f32x4 __attribute__((ext_vector_type(4)));
typedef unsigned int u32;

typedef __attribute__((address_space(1))) u32 gu32;
typedef __attribute__((address_space(3))) u32 lu32;

// mapped-LDS swizzled byte offset: row-stride 1024B, 16B chunks XOR'd by row&7
#define MLDS_OFF(row, col) (((row) << 10) + (((((col) >> 2) ^ ((row) & 7))) << 4) + (((col) & 3) << 2))

// ---------------------------------------------------------------------------
// prep: W'[k][n] = 0.5*W[k][n] + 0.5*K[(k-n+2) mod 256 if <5]
// stored as B-fragments for mfma_f32_16x16x32_f16:
//   frag f = kb*16+nb ; lane l holds W'[kb*32 + (l>>4)*8 + j][nb*16 + (l&15)], j=0..7
//   hi = f16(v) ; lo = f16((v - hi)*4096)   (scaled to avoid f16 denormals)
// ---------------------------------------------------------------------------
__global__ __launch_bounds__(256) void prep_w(const float* __restrict__ W,
                                              const float* __restrict__ Kl,
                                              f16* __restrict__ whi,
                                              f16* __restrict__ wlo)
{
    const int gwave = (int)(blockIdx.x * blockDim.x + threadIdx.x) >> 6;  // frag id 0..127
    const int l = (int)threadIdx.x & 63;
    if (gwave >= 128) return;
    const int kb = gwave >> 4, nb = gwave & 15;
    const int n = nb * 16 + (l & 15);
    const int kbase = kb * 32 + (l >> 4) * 8;
    f16 h[8], lo[8];
    #pragma unroll
    for (int j = 0; j < 8; ++j) {
        const int k = kbase + j;
        float v = 0.5f * W[k * C_DIM + n];
        const int d = (k - n + 2) & (C_DIM - 1);
        if (d < 5) v += 0.5f * Kl[d];
        const f16 hh = (f16)v;
        h[j] = hh;
        lo[j] = (f16)((v - (float)hh) * 4096.0f);
    }
    const size_t off = (size_t)gwave * 512 + (size_t)l * 8;   // f16 units; frag = 1 KiB
    *(f16x8*)(whi + off) = *(f16x8*)h;
    *(f16x8*)(wlo + off) = *(f16x8*)lo;
}

// ---------------------------------------------------------------------------
// main: 512 threads = 8 waves = (mb 0..3) x (nh 0..1); 64 rows/WG, 256 cols
// state g / mapped / beta*drive / params in regs (C-fragment layout:
//   lane l, frag nb, reg r  <->  row = mb*16 + (l>>4)*4 + r, col = nh*128 + nb*16 + (l&15))
// LDS: [0,64K) mapped f32 swizzled ; [64K,128K) W' stage double-buffer (2 x 32K)
// ---------------------------------------------------------------------------
__global__ __launch_bounds__(512, 2) void cml_main(
    const float* __restrict__ drive,
    const float* __restrict__ r_,
    const float* __restrict__ eps_,
    const float* __restrict__ beta_,
    const f16* __restrict__ whi,
    const f16* __restrict__ wlo,
    float* __restrict__ out)
{
    extern __shared__ char smem[];
    char* wstage = smem + 65536;

    const int tid = (int)threadIdx.x;
    const int w   = tid >> 6;           // wave 0..7
    const int l   = tid & 63;
    const int mb  = w & 3;
    const int nh  = w >> 2;
    const int kg  = l >> 4;             // 0..3
    const int cl  = l & 15;
    const size_t rowBase = (size_t)blockIdx.x * 64;

    // ---- one-time loads: params + drive (raw -> g, scaled -> drv) ----
    float rr[8], P1[8], P2[8];
    float g[8][4], m_[8][4], drv[8][4];
    #pragma unroll
    for (int nb = 0; nb < 8; ++nb) {
        const int c = nh * 128 + nb * 16 + cl;
        const float rv = r_[c], ev = eps_[c], bv = beta_[c];
        rr[nb] = rv;
        P1[nb] = (1.0f - bv) * (1.0f - ev);
        P2[nb] = (1.0f - bv) * ev;
        #pragma unroll
        for (int r = 0; r < 4; ++r) {
            const size_t row = rowBase + (size_t)(mb * 16 + kg * 4 + r);
            const float dv = drive[row * C_DIM + c];
            g[nb][r]   = dv;        // grid starts at drive
            drv[nb][r] = bv * dv;   // beta*drive folded
        }
    }

    f32x4 acch[8], accl[8];
    #pragma unroll
    for (int nb = 0; nb < 8; ++nb) {
        acch[nb] = (f32x4)0.0f;
        accl[nb] = (f32x4)0.0f;
    }

    // W' staging: per kb, 32 chunks of 1 KiB (16 hi frags + 16 lo frags);
    // wave w stages chunks w*4 .. w*4+3 via global_load_lds (dest linear, lane*16)
    auto stage_issue = [&](int kb, int buf) {
        #pragma unroll
        for (int i = 0; i < 4; ++i) {
            const int c = w * 4 + i;
            const f16* src = (c < 16) ? (whi + ((size_t)kb * 16 + c) * 512)
                                      : (wlo + ((size_t)kb * 16 + (c - 16)) * 512);
            gu32* gp = (gu32*)(src + (size_t)l * 8);
            lu32* lp = (lu32*)(wstage + (buf << 15) + (c << 10));
            __builtin_amdgcn_global_load_lds(gp, lp, 16, 0, 0);
        }
    };

    stage_issue(0, 0);

    #pragma unroll 1
    for (int s = 0; s < STEPS; ++s) {
        // ---- E: logistic map in regs + scatter mapped f32 to swizzled LDS ----
        #pragma unroll
        for (int nb = 0; nb < 8; ++nb) {
            #pragma unroll
            for (int r = 0; r < 4; ++r) {
                const float gv = g[nb][r];
                const float mv = rr[nb] * gv * (1.0f - gv);
                m_[nb][r] = mv;
                const int row = mb * 16 + kg * 4 + r;
                const int col = nh * 128 + nb * 16 + cl;
                *(float*)(smem + MLDS_OFF(row, col)) = mv;
            }
        }
        __syncthreads();   // mapped visible; kb0 stage drained (vmcnt0 at barrier)

        // ---- GEMM: coupled = mapped @ W'  (split-f16, 3 MFMAs per tile) ----
        #pragma unroll
        for (int kb = 0; kb < 8; ++kb) {
            const int buf = kb & 1;
            stage_issue((kb + 1) & 7, buf ^ 1);   // prefetch next kb (wraps to kb0: W' static)

            // A fragment: row mb*16+cl, cols kb*32 + kg*8 .. +7 (two swizzled 16B chunks)
            const int arow = mb * 16 + cl;
            const int ac0  = kb * 8 + kg * 2;
            const f32x4 a0 = *(const f32x4*)(smem + (arow << 10) + (((ac0    ) ^ (arow & 7)) << 4));
            const f32x4 a1 = *(const f32x4*)(smem + (arow << 10) + (((ac0 + 1) ^ (arow & 7)) << 4));
            const float af[8] = {a0.x, a0.y, a0.z, a0.w, a1.x, a1.y, a1.z, a1.w};
            f16x8 ahi, alo;
            #pragma unroll
            for (int j = 0; j < 8; ++j) {
                const f16 hh = (f16)af[j];
                ahi[j] = hh;
                alo[j] = (f16)((af[j] - (float)hh) * 4096.0f);
            }

            const char* wb = wstage + (buf << 15);
            #pragma unroll
            for (int nb = 0; nb < 8; ++nb) {
                const int nbg = nh * 8 + nb;
                const f16x8 bh = *(const f16x8*)(wb + (nbg << 10) + (l << 4));
                const f16x8 bl = *(const f16x8*)(wb + 16384 + (nbg << 10) + (l << 4));
                acch[nb] = __builtin_amdgcn_mfma_f32_16x16x32_f16(ahi, bh, acch[nb], 0, 0, 0);
                accl[nb] = __builtin_amdgcn_mfma_f32_16x16x32_f16(alo, bh, accl[nb], 0, 0, 0);
                accl[nb] = __builtin_amdgcn_mfma_f32_16x16x32_f16(ahi, bl, accl[nb], 0, 0, 0);
            }
            __syncthreads();   // drains next-kb stage; separates dbuf phases
        }

        // ---- physics: g = P1*m + P2*coupled + beta*drive (regs only) ----
        #pragma unroll
        for (int nb = 0; nb < 8; ++nb) {
            #pragma unroll
            for (int r = 0; r < 4; ++r) {
                const float coupled = acch[nb][r] + accl[nb][r] * (1.0f / 4096.0f);
                g[nb][r] = P1[nb] * m_[nb][r] + P2[nb] * coupled + drv[nb][r];
                acch[nb][r] = 0.0f;
                accl[nb][r] = 0.0f;
            }
        }
    }

    // ---- epilogue: clip + store ----
    #pragma unroll
    for (int nb = 0; nb < 8; ++nb) {
        #pragma unroll
        for (int r = 0; r < 4; ++r) {
            const size_t row = rowBase + (size_t)(mb * 16 + kg * 4 + r);
            const int col = nh * 128 + nb * 16 + cl;
            float v = g[nb][r];
            v = fminf(fmaxf(v, 1e-4f), 1.0f - 1e-4f);
            out[row * C_DIM + col] = v;
        }
    }
}

extern "C" void kernel_launch(void* const* d_in, const int* in_sizes, int n_in,
                              void* d_out, int out_size, void* d_ws, size_t ws_size,
                              hipStream_t stream) {
    (void)n_in; (void)ws_size; (void)out_size;
    const float* drive = (const float*)d_in[0];
    const float* r     = (const float*)d_in[1];
    const float* eps   = (const float*)d_in[2];
    const float* beta  = (const float*)d_in[3];
    const float* Kl    = (const float*)d_in[4];
    const float* W     = (const float*)d_in[5];
    float* out = (float*)d_out;

    f16* whi = (f16*)d_ws;            // 128 KiB
    f16* wlo = whi + 65536;           // 128 KiB

    prep_w<<<dim3(32), dim3(256), 0, stream>>>(W, Kl, whi, wlo);

    hipFuncSetAttribute((const void*)cml_main,
                        hipFuncAttributeMaxDynamicSharedMemorySize, 131072);

    const int nrows = in_sizes[0] / C_DIM;        // 131072
    cml_main<<<dim3((unsigned)(nrows / 64)), dim3(512), 131072, stream>>>(
        drive, r, eps, beta, whi, wlo, out);
}

// Round 3
// 792.778 us; speedup vs baseline: 5.9256x; 4.3659x over previous
//
#include <hip/hip_runtime.h>

#define C_DIM 256
#define STEPS 20
#define ROWS_PER_WG 32

typedef _Float16 f16;
typedef f16 f16x8 __attribute__((ext_vector_type(8)));
typedef float f32x4 __attribute__((ext_vector_type(4)));

// ---------------------------------------------------------------------------
// prep: W'[k][n] = 0.5*W[k][n] + 0.5*K[(k-n+2) mod 256 if <5]
// stored as B-fragments for mfma_f32_16x16x32_f16:
//   frag f = kb*16+nb ; lane l holds W'[kb*32 + (l>>4)*8 + j][nb*16 + (l&15)]
//   hi = f16(v) ; lo = f16((v - hi)*4096)
// ---------------------------------------------------------------------------
__global__ __launch_bounds__(256) void prep_w(const float* __restrict__ W,
                                              const float* __restrict__ Kl,
                                              f16* __restrict__ whi,
                                              f16* __restrict__ wlo)
{
    const int gwave = (int)(blockIdx.x * blockDim.x + threadIdx.x) >> 6;  // frag id 0..127
    const int l = (int)threadIdx.x & 63;
    if (gwave >= 128) return;
    const int kb = gwave >> 4, nb = gwave & 15;
    const int n = nb * 16 + (l & 15);
    const int kbase = kb * 32 + (l >> 4) * 8;
    f16 h[8], lo[8];
    #pragma unroll
    for (int j = 0; j < 8; ++j) {
        const int k = kbase + j;
        float v = 0.5f * W[k * C_DIM + n];
        const int d = (k - n + 2) & (C_DIM - 1);
        if (d < 5) v += 0.5f * Kl[d];
        const f16 hh = (f16)v;
        h[j] = hh;
        lo[j] = (f16)((v - (float)hh) * 4096.0f);
    }
    const size_t off = (size_t)gwave * 512 + (size_t)l * 8;
    *(f16x8*)(whi + off) = *(f16x8*)h;
    *(f16x8*)(wlo + off) = *(f16x8*)lo;
}

// ---------------------------------------------------------------------------
// main: 512 thr = 8 waves; wave w owns output cols [w*32, w*32+32) for all
// 32 rows of the WG. B fragments (hi+lo, all 8 kb) live in 128 VGPRs per
// wave for the whole kernel — the step loop touches NO global memory.
// LDS: mapped activations as f16 hi/lo planes, double-buffered:
//   buf b at smem + b*32768 ; hi plane 16K, lo plane +16384
//   swizzled: byte = row*512 + ((chunk ^ (row&7))<<4) + (col&7)*2, chunk=col>>3
// One __syncthreads per step (between plane-write and plane-read; double
// buffering makes read(s) vs write(s+1) collision-free, and the s+1 barrier
// orders read(s) vs write(s+2)).
// ---------------------------------------------------------------------------
__global__ __launch_bounds__(512, 2) void cml_main(
    const float* __restrict__ drive,
    const float* __restrict__ r_,
    const float* __restrict__ eps_,
    const float* __restrict__ beta_,
    const f16* __restrict__ whi,
    const f16* __restrict__ wlo,
    float* __restrict__ out)
{
    __shared__ char smem[65536];

    const int tid = (int)threadIdx.x;
    const int w   = tid >> 6;            // wave 0..7
    const int l   = tid & 63;
    const int kg  = l >> 4;              // 0..3
    const int cl  = l & 15;
    const int wcol0 = w * 32;
    const size_t rowBase = (size_t)blockIdx.x * ROWS_PER_WG;

    // ---- one-time: B fragments into registers (32 frags = 128 VGPRs) ----
    f16x8 Bh[8][2], Bl[8][2];
    #pragma unroll
    for (int kb = 0; kb < 8; ++kb) {
        #pragma unroll
        for (int nb = 0; nb < 2; ++nb) {
            const size_t f = (size_t)(kb * 16 + w * 2 + nb) * 512 + (size_t)l * 8;
            Bh[kb][nb] = *(const f16x8*)(whi + f);
            Bl[kb][nb] = *(const f16x8*)(wlo + f);
        }
    }

    // ---- one-time: params + drive (C-fragment layout) ----
    float rr[2], P1[2], P2[2];
    float g[2][2][4], m_[2][2][4], drv[2][2][4];
    #pragma unroll
    for (int nb = 0; nb < 2; ++nb) {
        const int c = wcol0 + nb * 16 + cl;
        const float rv = r_[c], ev = eps_[c], bv = beta_[c];
        rr[nb] = rv;
        P1[nb] = (1.0f - bv) * (1.0f - ev);
        P2[nb] = (1.0f - bv) * ev;
        #pragma unroll
        for (int mb = 0; mb < 2; ++mb) {
            #pragma unroll
            for (int r = 0; r < 4; ++r) {
                const size_t row = rowBase + (size_t)(mb * 16 + kg * 4 + r);
                const float dv = drive[row * C_DIM + c];
                g[mb][nb][r]   = dv;       // grid starts at drive
                drv[mb][nb][r] = bv * dv;  // beta*drive folded
            }
        }
    }

    f32x4 acch[2][2], accl[2][2];
    #pragma unroll
    for (int mb = 0; mb < 2; ++mb)
        #pragma unroll
        for (int nb = 0; nb < 2; ++nb) {
            acch[mb][nb] = (f32x4)0.0f;
            accl[mb][nb] = (f32x4)0.0f;
        }

    #pragma unroll 1
    for (int s = 0; s < STEPS; ++s) {
        char* ph = smem + ((s & 1) << 15);
        char* pl = ph + 16384;

        // ---- E: logistic map + f32->f16 hi/lo split, scatter to planes ----
        #pragma unroll
        for (int mb = 0; mb < 2; ++mb) {
            #pragma unroll
            for (int nb = 0; nb < 2; ++nb) {
                const int chunk = (wcol0 >> 3) + nb * 2 + (cl >> 3);
                #pragma unroll
                for (int r = 0; r < 4; ++r) {
                    const float gv = g[mb][nb][r];
                    const float mv = rr[nb] * gv * (1.0f - gv);
                    m_[mb][nb][r] = mv;
                    const f16 hh = (f16)mv;
                    const f16 ll = (f16)((mv - (float)hh) * 4096.0f);
                    const int row = mb * 16 + kg * 4 + r;
                    const int off = (row << 9) + (((chunk ^ (row & 7))) << 4) + ((cl & 7) << 1);
                    *(f16*)(ph + off) = hh;
                    *(f16*)(pl + off) = ll;
                }
            }
        }
        __syncthreads();

        // ---- GEMM: coupled = mapped @ W'  (split-f16, 3 MFMAs/tile) ----
        #pragma unroll
        for (int kb = 0; kb < 8; ++kb) {
            #pragma unroll
            for (int mb = 0; mb < 2; ++mb) {
                const int arow = mb * 16 + cl;
                const int aoff = (arow << 9) + (((kb * 4 + kg) ^ (arow & 7)) << 4);
                const f16x8 ahi = *(const f16x8*)(ph + aoff);
                const f16x8 alo = *(const f16x8*)(pl + aoff);
                #pragma unroll
                for (int nb = 0; nb < 2; ++nb) {
                    acch[mb][nb] = __builtin_amdgcn_mfma_f32_16x16x32_f16(ahi, Bh[kb][nb], acch[mb][nb], 0, 0, 0);
                    accl[mb][nb] = __builtin_amdgcn_mfma_f32_16x16x32_f16(alo, Bh[kb][nb], accl[mb][nb], 0, 0, 0);
                    accl[mb][nb] = __builtin_amdgcn_mfma_f32_16x16x32_f16(ahi, Bl[kb][nb], accl[mb][nb], 0, 0, 0);
                }
            }
        }

        // ---- physics (regs only) ----
        #pragma unroll
        for (int mb = 0; mb < 2; ++mb) {
            #pragma unroll
            for (int nb = 0; nb < 2; ++nb) {
                #pragma unroll
                for (int r = 0; r < 4; ++r) {
                    const float coupled = acch[mb][nb][r] + accl[mb][nb][r] * (1.0f / 4096.0f);
                    g[mb][nb][r] = P1[nb] * m_[mb][nb][r] + P2[nb] * coupled + drv[mb][nb][r];
                    acch[mb][nb][r] = 0.0f;
                    accl[mb][nb][r] = 0.0f;
                }
            }
        }
    }

    // ---- epilogue: clip + store ----
    #pragma unroll
    for (int mb = 0; mb < 2; ++mb) {
        #pragma unroll
        for (int nb = 0; nb < 2; ++nb) {
            const int c = wcol0 + nb * 16 + cl;
            #pragma unroll
            for (int r = 0; r < 4; ++r) {
                const size_t row = rowBase + (size_t)(mb * 16 + kg * 4 + r);
                float v = g[mb][nb][r];
                v = fminf(fmaxf(v, 1e-4f), 1.0f - 1e-4f);
                out[row * C_DIM + c] = v;
            }
        }
    }
}

extern "C" void kernel_launch(void* const* d_in, const int* in_sizes, int n_in,
                              void* d_out, int out_size, void* d_ws, size_t ws_size,
                              hipStream_t stream) {
    (void)n_in; (void)ws_size; (void)out_size;
    const float* drive = (const float*)d_in[0];
    const float* r     = (const float*)d_in[1];
    const float* eps   = (const float*)d_in[2];
    const float* beta  = (const float*)d_in[3];
    const float* Kl    = (const float*)d_in[4];
    const float* W     = (const float*)d_in[5];
    float* out = (float*)d_out;

    f16* whi = (f16*)d_ws;            // 128 KiB
    f16* wlo = whi + 65536;           // 128 KiB

    prep_w<<<dim3(32), dim3(256), 0, stream>>>(W, Kl, whi, wlo);

    const int nrows = in_sizes[0] / C_DIM;        // 131072
    cml_main<<<dim3((unsigned)(nrows / ROWS_PER_WG)), dim3(512), 0, stream>>>(
        drive, r, eps, beta, whi, wlo, out);
}